// Round 1
// baseline (606.130 us; speedup 1.0000x reference)
//
#include <hip/hip_runtime.h>
#include <math.h>

// LSTM (Keras gate order i,f,c,o; activation=relu, recurrent_activation=sigmoid)
// + Dense(64, sigmoid) + row-sum normalize.
// B=4096, T=256, F=64, H=16, 4H=64, D=64. All fp32.
//
// Decomposition: one wave64 per batch row; lane = gate index g in [0,64).
// Lane g holds column g of W (64 regs) and U (16 regs). Per timestep the
// wave loads x[b][t][:] (lane-uniform data, coalesced float4 covering 4
// timesteps per load) and broadcasts each x value via v_readlane (constant
// lane index -> SGPR operand FMA; avoids DS-pipe bpermute storms).
// h/c state for unit (lane&15) is replicated in all 4 lane groups, so
// readlane(h,k) k<16 is a valid broadcast of h[k].

#define T_STEPS 256
#define F_DIM 64
#define H_DIM 16
#define G_DIM 64   // 4*H

__device__ __forceinline__ float rl(float v, int srclane) {
    return __uint_as_float(__builtin_amdgcn_readlane(__float_as_uint(v), srclane));
}

__device__ __forceinline__ float fast_sigmoid(float z) {
    // ~2 ulp: v_exp + v_rcp. Plenty vs 4e-4 output threshold.
    return __builtin_amdgcn_rcpf(1.0f + __expf(-z));
}

__global__ __launch_bounds__(256, 4)
void lstm_fused_kernel(const float* __restrict__ x,
                       const float* __restrict__ W,
                       const float* __restrict__ U,
                       const float* __restrict__ bias,
                       const float* __restrict__ Wd,
                       const float* __restrict__ bd,
                       float* __restrict__ out)
{
    const int lane = threadIdx.x & 63;
    const int wid  = threadIdx.x >> 6;
    const int b    = blockIdx.x * 4 + wid;   // 1024 blocks x 4 waves = 4096 rows

    // Per-lane weight columns: W[f][lane], U[k][lane] (coalesced loads).
    float Wcol[F_DIM];
    #pragma unroll
    for (int f = 0; f < F_DIM; ++f) Wcol[f] = W[f * G_DIM + lane];
    float Ucol[H_DIM];
    #pragma unroll
    for (int k = 0; k < H_DIM; ++k) Ucol[k] = U[k * G_DIM + lane];
    const float bg = bias[lane];

    const float* xrow = x + (size_t)b * T_STEPS * F_DIM;

    const int grp  = lane >> 4;    // 0:i 1:f 2:g(cand) 3:o
    const int base = lane & 15;    // unit index within gate

    float h = 0.0f, c = 0.0f;      // state for unit `base` (replicated x4 groups)

    for (int t0 = 0; t0 < T_STEPS; t0 += 4) {
        // 4 timesteps = 256 floats = one coalesced 1KB wave load.
        // flat element idx e = 4*lane + j  -> timestep r = e>>6, f = e&63.
        // For (r, f): source lane = r*16 + (f>>2), component = f&3.
        const float4 xq = *(const float4*)(xrow + t0 * F_DIM + lane * 4);

        #pragma unroll
        for (int r = 0; r < 4; ++r) {
            float z = bg;
            // x @ W  (broadcast x via readlane -> SGPR, FMA with Wcol)
            #pragma unroll
            for (int f = 0; f < F_DIM; ++f) {
                const int src = r * 16 + (f >> 2);
                float xs;
                switch (f & 3) {
                    case 0:  xs = rl(xq.x, src); break;
                    case 1:  xs = rl(xq.y, src); break;
                    case 2:  xs = rl(xq.z, src); break;
                    default: xs = rl(xq.w, src); break;
                }
                z = fmaf(xs, Wcol[f], z);
            }
            // h @ U  (h[k] lives replicated; lane k holds unit k)
            #pragma unroll
            for (int k = 0; k < H_DIM; ++k)
                z = fmaf(rl(h, k), Ucol[k], z);

            // activations (branchless select: lanes 32..47 are candidate/relu)
            const float sig = fast_sigmoid(z);
            const float rel = fmaxf(z, 0.0f);
            const float a   = (grp == 2) ? rel : sig;

            // gather i,f,g,o for unit `base` (4 true shuffles/step)
            const float gi = __shfl(a, base);
            const float gf = __shfl(a, base + 16);
            const float gg = __shfl(a, base + 32);
            const float go = __shfl(a, base + 48);

            c = fmaf(gf, c, gi * gg);
            h = go * fmaxf(c, 0.0f);
        }
    }

    // Dense(64) + sigmoid + sum-normalize. lane = output dim d.
    float acc = bd[lane];
    #pragma unroll
    for (int k = 0; k < H_DIM; ++k)
        acc = fmaf(rl(h, k), Wd[k * G_DIM + lane], acc);
    float o = fast_sigmoid(acc);

    float s = o;
    #pragma unroll
    for (int off = 32; off > 0; off >>= 1)
        s += __shfl_xor(s, off);

    out[(size_t)b * G_DIM + lane] = o / s;
}

extern "C" void kernel_launch(void* const* d_in, const int* in_sizes, int n_in,
                              void* d_out, int out_size, void* d_ws, size_t ws_size,
                              hipStream_t stream) {
    const float* x    = (const float*)d_in[0];   // [4096, 256, 64]
    const float* W    = (const float*)d_in[1];   // [64, 64]
    const float* U    = (const float*)d_in[2];   // [16, 64]
    const float* bias = (const float*)d_in[3];   // [64]
    const float* Wd   = (const float*)d_in[4];   // [16, 64]
    const float* bd   = (const float*)d_in[5];   // [64]
    float* out        = (float*)d_out;           // [4096, 64]

    const int n_rows = in_sizes[0] / (T_STEPS * F_DIM);   // 4096
    dim3 grid(n_rows / 4), block(256);
    lstm_fused_kernel<<<grid, block, 0, stream>>>(x, W, U, bias, Wd, bd, out);
}

// Round 3
// 388.461 us; speedup vs baseline: 1.5603x; 1.5603x over previous
//
#include <hip/hip_runtime.h>
#include <math.h>

// Fused LSTM (Keras gates i,f,c~,o; act=relu, rec_act=sigmoid) + Dense(64,sigmoid)
// + row-sum normalize.  B=4096, T=256, F=64, H=16, 4H=64, D=64, fp32 in/out.
//
// One wave64 per batch row (4096 waves = 4/SIMD). Per 16-timestep chunk:
//   xw = x@W + b via mfma_f32_16x16x32_f16 (8 MFMAs; W frags resident in VGPRs,
//   bias folded into the C init), C-layout scattered to wave-private LDS
//   (row stride 68 floats -> <=2-way banks = free), then 16 recurrence steps:
//   z[g] = 1 ds_read; h@U = 16x(readlane+fmac); gate combine with only 2
//   shuffles (xor32, xor16); c valid in lanes 0..31, h valid in lanes
//   16..31 (readlane(h,16+k) broadcasts it).
// f16 error budget: dz ~ 5e-4 -> gates ~1.2e-4 -> out ~1e-5 << 3.96e-4 thresh.

#define T_STEPS 256
#define F_DIM   64
#define ROW_ELEMS (T_STEPS * F_DIM)      // 16384
#define LDS_STRIDE 68                    // 64 + 4 pad: write phase 2-way, read 2-way
#define LDS_PER_WAVE (16 * LDS_STRIDE)   // 1088 floats

typedef __fp16   g2 __attribute__((ext_vector_type(2)));   // cvt_pkrtz result type
typedef _Float16 h8 __attribute__((ext_vector_type(8)));   // MFMA operand type
typedef float    f4 __attribute__((ext_vector_type(4)));

union H8 { h8 v; g2 p[4]; };   // same bits, different clang vector elt types

__device__ __forceinline__ float rl(float v, int srclane) {
    return __uint_as_float(__builtin_amdgcn_readlane(__float_as_uint(v), srclane));
}
__device__ __forceinline__ float fast_sigmoid(float z) {
    return __builtin_amdgcn_rcpf(1.0f + __expf(-z));
}

__global__ __launch_bounds__(256, 4)
void lstm_fused_kernel(const float* __restrict__ x,
                       const float* __restrict__ W,
                       const float* __restrict__ U,
                       const float* __restrict__ bias,
                       const float* __restrict__ Wd,
                       const float* __restrict__ bd,
                       float* __restrict__ out)
{
    __shared__ float sh[4 * LDS_PER_WAVE];   // 17408 B, wave-private quarters

    const int lane = threadIdx.x & 63;
    const int wid  = threadIdx.x >> 6;
    const int b    = blockIdx.x * 4 + wid;   // 1024 blocks x 4 waves

    const int tRow = lane & 15;              // MFMA A row (timestep-in-chunk)
    const int q    = lane >> 4;              // quad: k-group for A/B frags; gate group
    float* const wsh = sh + wid * LDS_PER_WAVE;

    // ---- W as MFMA B-fragments (f16), held in 32 VGPRs. B[k][n]: n=lane&15,
    // k = q*8+j (+32 for k-chunk 1). Frag index [2*tt + c].
    h8 Wf[8];
    #pragma unroll
    for (int tt = 0; tt < 4; ++tt) {
        const int col = tt * 16 + tRow;
        #pragma unroll
        for (int c = 0; c < 2; ++c) {
            H8 u;
            #pragma unroll
            for (int jp = 0; jp < 4; ++jp) {
                const int row = c * 32 + q * 8 + jp * 2;
                u.p[jp] = __builtin_amdgcn_cvt_pkrtz(W[row * 64 + col],
                                                     W[(row + 1) * 64 + col]);
            }
            Wf[2 * tt + c] = u.v;
        }
    }

    // bias for C init: col = tt*16 + tRow
    float bcol[4];
    #pragma unroll
    for (int tt = 0; tt < 4; ++tt) bcol[tt] = bias[tt * 16 + tRow];

    // recurrent weights, per-lane column
    float Ucol[16];
    #pragma unroll
    for (int k = 0; k < 16; ++k) Ucol[k] = U[k * 64 + lane];

    // per-lane A-load pointer: row t0+tRow, features q*8.. (k-chunk c adds +32)
    const float* ap = x + (size_t)b * ROW_ELEMS + tRow * F_DIM + q * 8;

    float4 xv0 = *(const float4*)(ap + 0);
    float4 xv1 = *(const float4*)(ap + 4);
    float4 xv2 = *(const float4*)(ap + 32);
    float4 xv3 = *(const float4*)(ap + 36);

    float h = 0.0f, c = 0.0f;

    for (int ch = 0; ch < 16; ++ch) {
        // ---- convert prefetched x to f16 A-frags
        H8 a0, a1;
        a0.p[0] = __builtin_amdgcn_cvt_pkrtz(xv0.x, xv0.y);
        a0.p[1] = __builtin_amdgcn_cvt_pkrtz(xv0.z, xv0.w);
        a0.p[2] = __builtin_amdgcn_cvt_pkrtz(xv1.x, xv1.y);
        a0.p[3] = __builtin_amdgcn_cvt_pkrtz(xv1.z, xv1.w);
        a1.p[0] = __builtin_amdgcn_cvt_pkrtz(xv2.x, xv2.y);
        a1.p[1] = __builtin_amdgcn_cvt_pkrtz(xv2.z, xv2.w);
        a1.p[2] = __builtin_amdgcn_cvt_pkrtz(xv3.x, xv3.y);
        a1.p[3] = __builtin_amdgcn_cvt_pkrtz(xv3.z, xv3.w);

        // ---- xw = x@W + bias  (8 MFMAs)
        f4 acc[4];
        #pragma unroll
        for (int tt = 0; tt < 4; ++tt) {
            acc[tt] = (f4){bcol[tt], bcol[tt], bcol[tt], bcol[tt]};
            acc[tt] = __builtin_amdgcn_mfma_f32_16x16x32_f16(a0.v, Wf[2 * tt],     acc[tt], 0, 0, 0);
            acc[tt] = __builtin_amdgcn_mfma_f32_16x16x32_f16(a1.v, Wf[2 * tt + 1], acc[tt], 0, 0, 0);
        }

        // ---- prefetch next chunk's x (hidden under the 16-step recurrence)
        if (ch < 15) {
            const float* np = ap + (ch + 1) * (16 * F_DIM);
            xv0 = *(const float4*)(np + 0);
            xv1 = *(const float4*)(np + 4);
            xv2 = *(const float4*)(np + 32);
            xv3 = *(const float4*)(np + 36);
        }

        // ---- scatter C-layout -> LDS [t][g] (row=q*4+r, col=tt*16+tRow)
        #pragma unroll
        for (int tt = 0; tt < 4; ++tt)
            #pragma unroll
            for (int r = 0; r < 4; ++r)
                wsh[(q * 4 + r) * LDS_STRIDE + tt * 16 + tRow] = acc[tt][r];

        // ---- 16 recurrence steps
        #pragma unroll
        for (int t = 0; t < 16; ++t) {
            float z0 = wsh[t * LDS_STRIDE + lane];   // xw + bias for gate `lane`
            float z1 = 0.0f;
            #pragma unroll
            for (int k = 0; k < 8; ++k)  z0 = fmaf(rl(h, 16 + k), Ucol[k], z0);
            #pragma unroll
            for (int k = 8; k < 16; ++k) z1 = fmaf(rl(h, 16 + k), Ucol[k], z1);
            const float zz = z0 + z1;

            const float sig = fast_sigmoid(zz);
            const float a   = (q == 2) ? fmaxf(zz, 0.0f) : sig;   // candidate=relu

            // q0 receives g, q1 receives o
            const float r1 = __shfl_xor(a, 32);
            // q0: i*g ; q1: f*c
            const float m1 = a * ((lane < 16) ? r1 : c);
            // swap q0<->q1 partials; c valid in lanes 0..31
            const float r2 = __shfl_xor(m1, 16);
            c = m1 + r2;
            // h valid in lanes 16..31 (r1 there = o)
            h = r1 * fmaxf(c, 0.0f);
        }
    }

    // ---- Dense(64, sigmoid) + sum-normalize; lane = output dim
    float hacc = bd[lane];
    #pragma unroll
    for (int k = 0; k < 16; ++k)
        hacc = fmaf(rl(h, 16 + k), Wd[k * 64 + lane], hacc);
    const float o = fast_sigmoid(hacc);

    float s = o;
    #pragma unroll
    for (int off = 32; off > 0; off >>= 1) s += __shfl_xor(s, off);

    out[(size_t)b * 64 + lane] = o * __builtin_amdgcn_rcpf(s);
}

extern "C" void kernel_launch(void* const* d_in, const int* in_sizes, int n_in,
                              void* d_out, int out_size, void* d_ws, size_t ws_size,
                              hipStream_t stream) {
    const float* x    = (const float*)d_in[0];   // [4096, 256, 64]
    const float* W    = (const float*)d_in[1];   // [64, 64]
    const float* U    = (const float*)d_in[2];   // [16, 64]
    const float* bias = (const float*)d_in[3];   // [64]
    const float* Wd   = (const float*)d_in[4];   // [16, 64]
    const float* bd   = (const float*)d_in[5];   // [64]
    float* out        = (float*)d_out;           // [4096, 64]

    const int n_rows = in_sizes[0] / ROW_ELEMS;  // 4096
    dim3 grid(n_rows / 4), block(256);
    lstm_fused_kernel<<<grid, block, 0, stream>>>(x, W, U, bias, Wd, bd, out);
}

// Round 5
// 373.768 us; speedup vs baseline: 1.6217x; 1.0393x over previous
//
#include <hip/hip_runtime.h>
#include <math.h>

// Fused LSTM (Keras gates i,f,c~,o; act=relu, rec_act=sigmoid) + Dense(64,sigmoid)
// + row-sum normalize.  B=4096, T=256, F=64, H=16, 4H=64, D=64, fp32 in/out.
//
// One wave64 per FOUR batch rows; 16 lanes per row, lane = unit k, all four
// gates of unit k in-lane (float2 packs -> v_pk_fma_f32). No cross-lane ops in
// the serial chain: h broadcast via tiny LDS buffer (write_b32 + 4 broadcast
// read_b128 per step), gate combine in-lane.
//
// Precision: round-4's single-f16 x@W measured 4.9e-4 > 3.96e-4 threshold.
// Now error-compensated split: x=x_hi+x_lo, W=W_hi+W_lo (f16 each, residuals
// exact in fp32); z = hi*hi + lo*hi + hi*lo chained into one fp32 MFMA
// accumulator. Dropped lo*lo ~ 2.4e-7 rel -> z effectively fp32-exact
// (round-1 proved the fp32 pipeline hits absmax ~0).
// 24 MFMAs/row/chunk (~460 cyc/chunk) still << HBM arrival (~6.1k cyc/chunk).

#define T_STEPS 256
#define F_DIM   64
#define ROW_ELEMS (T_STEPS * F_DIM)      // 16384

typedef _Float16 h8  __attribute__((ext_vector_type(8)));   // MFMA operand (4 VGPRs)
typedef float    f4v __attribute__((ext_vector_type(4)));
typedef float    f2v __attribute__((ext_vector_type(2)));

union H8s { h8 v; _Float16 e[8]; };

__device__ __forceinline__ float fast_sigmoid(float z) {
    return __builtin_amdgcn_rcpf(1.0f + __expf(-z));
}

// split one float4 into f16 hi + f16 lo fragments (elements o..o+3)
__device__ __forceinline__ void split4(const float4 v, H8s& hi, H8s& lo, int o) {
    const float f[4] = {v.x, v.y, v.z, v.w};
    #pragma unroll
    for (int i = 0; i < 4; ++i) {
        const _Float16 h = (_Float16)f[i];            // RTE
        hi.e[o + i] = h;
        lo.e[o + i] = (_Float16)(f[i] - (float)h);    // residual exact in fp32
    }
}

__global__ __launch_bounds__(64, 1)
void lstm_fused_kernel(const float* __restrict__ x,
                       const float* __restrict__ W,
                       const float* __restrict__ U,
                       const float* __restrict__ bias,
                       const float* __restrict__ Wd,
                       const float* __restrict__ bd,
                       float* __restrict__ out)
{
    __shared__ float4 xwbuf[4][16][16];   // [row][t][unit] = (zi,zf,zg,zo)  16 KB
    __shared__ float4 hb4[4][4];          // [row][j4] h broadcast buffer    256 B

    const int lane = threadIdx.x;        // block = 1 wave
    const int k    = lane & 15;          // unit; MFMA B-col n; C col
    const int q    = lane >> 4;          // MFMA k-group; C row group
    const int b0   = blockIdx.x * 4;

    // ---- W as hi/lo f16 MFMA B-fragments (layout validated rounds 3/4).
    // B[kdim][n]: n = tt*16+k slice col, kdim = cc*32 + q*8 + j.
    h8 Whi[8], Wlo[8];
    #pragma unroll
    for (int tt = 0; tt < 4; ++tt) {
        const int col = tt * 16 + k;
        #pragma unroll
        for (int cc = 0; cc < 2; ++cc) {
            H8s uh, ul;
            #pragma unroll
            for (int j = 0; j < 8; ++j) {
                const float w = W[(cc * 32 + q * 8 + j) * 64 + col];
                const _Float16 wh = (_Float16)w;
                uh.e[j] = wh;
                ul.e[j] = (_Float16)(w - (float)wh);
            }
            Whi[2 * tt + cc] = uh.v;
            Wlo[2 * tt + cc] = ul.v;
        }
    }

    // ---- recurrent weights as float2 packs: (gate k, 16+k) / (32+k, 48+k)
    f2v Uif[16], Ugo[16];
    #pragma unroll
    for (int j = 0; j < 16; ++j) {
        Uif[j] = (f2v){U[j * 64 + k],      U[j * 64 + 16 + k]};
        Ugo[j] = (f2v){U[j * 64 + 32 + k], U[j * 64 + 48 + k]};
    }
    const f2v bif = (f2v){bias[k],      bias[16 + k]};
    const f2v bgo = (f2v){bias[32 + k], bias[48 + k]};

    // ---- A-operand pointers per row + prefetch chunk 0
    const float* ap0 = x + (size_t)(b0 + 0) * ROW_ELEMS + k * F_DIM + q * 8;
    const float* ap[4] = {ap0, ap0 + ROW_ELEMS, ap0 + 2 * ROW_ELEMS, ap0 + 3 * ROW_ELEMS};

    float4 xv[4][4];
    #pragma unroll
    for (int r = 0; r < 4; ++r) {
        xv[r][0] = *(const float4*)(ap[r] + 0);
        xv[r][1] = *(const float4*)(ap[r] + 4);
        xv[r][2] = *(const float4*)(ap[r] + 32);
        xv[r][3] = *(const float4*)(ap[r] + 36);
    }

    // h-broadcast buffer init (64 lanes cover 4 rows x 16 units)
    ((float*)&hb4[q][0])[k] = 0.0f;
    __asm__ __volatile__("" ::: "memory");

    float h = 0.0f, c = 0.0f;

    for (int ch = 0; ch < 16; ++ch) {
        // ---- xw = x@W for 4 rows (24 MFMAs each: hi*hi + lo*hi + hi*lo)
        #pragma unroll
        for (int r = 0; r < 4; ++r) {
            H8s a0h, a0l, a1h, a1l;
            split4(xv[r][0], a0h, a0l, 0);
            split4(xv[r][1], a0h, a0l, 4);
            split4(xv[r][2], a1h, a1l, 0);
            split4(xv[r][3], a1h, a1l, 4);

            f4v acc[4];
            #pragma unroll
            for (int tt = 0; tt < 4; ++tt) {
                acc[tt] = (f4v){0.0f, 0.0f, 0.0f, 0.0f};
                acc[tt] = __builtin_amdgcn_mfma_f32_16x16x32_f16(a0h.v, Whi[2 * tt],     acc[tt], 0, 0, 0);
                acc[tt] = __builtin_amdgcn_mfma_f32_16x16x32_f16(a1h.v, Whi[2 * tt + 1], acc[tt], 0, 0, 0);
                acc[tt] = __builtin_amdgcn_mfma_f32_16x16x32_f16(a0l.v, Whi[2 * tt],     acc[tt], 0, 0, 0);
                acc[tt] = __builtin_amdgcn_mfma_f32_16x16x32_f16(a1l.v, Whi[2 * tt + 1], acc[tt], 0, 0, 0);
                acc[tt] = __builtin_amdgcn_mfma_f32_16x16x32_f16(a0h.v, Wlo[2 * tt],     acc[tt], 0, 0, 0);
                acc[tt] = __builtin_amdgcn_mfma_f32_16x16x32_f16(a1h.v, Wlo[2 * tt + 1], acc[tt], 0, 0, 0);
            }
            // C layout: lane (q,k) holds C[m=q*4+r_][n in {k,16+k,32+k,48+k}]
            #pragma unroll
            for (int r_ = 0; r_ < 4; ++r_)
                xwbuf[r][q * 4 + r_][k] =
                    make_float4(acc[0][r_], acc[1][r_], acc[2][r_], acc[3][r_]);
        }
        __asm__ __volatile__("" ::: "memory");

        // ---- prefetch next chunk (hidden under the 16 recurrence steps)
        if (ch < 15) {
            #pragma unroll
            for (int r = 0; r < 4; ++r) {
                const float* np = ap[r] + (ch + 1) * (16 * F_DIM);
                xv[r][0] = *(const float4*)(np + 0);
                xv[r][1] = *(const float4*)(np + 4);
                xv[r][2] = *(const float4*)(np + 32);
                xv[r][3] = *(const float4*)(np + 36);
            }
        }

        // ---- 16 recurrence steps, all-in-lane gates
        #pragma unroll
        for (int t = 0; t < 16; ++t) {
            const float4 xw4 = xwbuf[q][t][k];
            const float4 h0 = hb4[q][0];   // broadcast reads (same addr per row)
            const float4 h1 = hb4[q][1];
            const float4 h2 = hb4[q][2];
            const float4 h3 = hb4[q][3];
            const float hj[16] = {h0.x, h0.y, h0.z, h0.w,
                                  h1.x, h1.y, h1.z, h1.w,
                                  h2.x, h2.y, h2.z, h2.w,
                                  h3.x, h3.y, h3.z, h3.w};

            f2v zif  = bif + (f2v){xw4.x, xw4.y};
            f2v zgo  = bgo + (f2v){xw4.z, xw4.w};
            f2v zif2 = (f2v){0.0f, 0.0f};
            f2v zgo2 = (f2v){0.0f, 0.0f};
            #pragma unroll
            for (int j = 0; j < 16; j += 2) {
                const f2v ha = (f2v){hj[j],     hj[j]};
                const f2v hb = (f2v){hj[j + 1], hj[j + 1]};
                zif  = ha * Uif[j]     + zif;     // v_pk_fma_f32
                zgo  = ha * Ugo[j]     + zgo;
                zif2 = hb * Uif[j + 1] + zif2;
                zgo2 = hb * Ugo[j + 1] + zgo2;
            }
            zif += zif2;
            zgo += zgo2;

            const float gi = fast_sigmoid(zif.x);
            const float gf = fast_sigmoid(zif.y);
            const float gg = fmaxf(zgo.x, 0.0f);   // candidate: relu
            const float go = fast_sigmoid(zgo.y);

            c = fmaf(gf, c, gi * gg);
            h = go * fmaxf(c, 0.0f);

            ((float*)&hb4[q][0])[k] = h;           // publish for next step
            __asm__ __volatile__("" ::: "memory"); // pin LDS write->read order
        }
    }

    // ---- Dense(64, sigmoid) + row-sum normalize; lane covers d = {k,16+k,32+k,48+k}
    const float4 H0 = hb4[q][0], H1 = hb4[q][1], H2 = hb4[q][2], H3 = hb4[q][3];
    const float hj[16] = {H0.x, H0.y, H0.z, H0.w,
                          H1.x, H1.y, H1.z, H1.w,
                          H2.x, H2.y, H2.z, H2.w,
                          H3.x, H3.y, H3.z, H3.w};

    f2v aif = (f2v){bd[k],      bd[16 + k]};
    f2v ago = (f2v){bd[32 + k], bd[48 + k]};
    #pragma unroll
    for (int j = 0; j < 16; ++j) {
        const f2v wif = (f2v){Wd[j * 64 + k],      Wd[j * 64 + 16 + k]};
        const f2v wgo = (f2v){Wd[j * 64 + 32 + k], Wd[j * 64 + 48 + k]};
        const f2v hjj = (f2v){hj[j], hj[j]};
        aif = hjj * wif + aif;
        ago = hjj * wgo + ago;
    }
    const float o0 = fast_sigmoid(aif.x);
    const float o1 = fast_sigmoid(aif.y);
    const float o2 = fast_sigmoid(ago.x);
    const float o3 = fast_sigmoid(ago.y);

    float s = o0 + o1 + o2 + o3;
    s += __shfl_xor(s, 1);
    s += __shfl_xor(s, 2);
    s += __shfl_xor(s, 4);
    s += __shfl_xor(s, 8);
    const float rs = __builtin_amdgcn_rcpf(s);

    float* orow = out + (size_t)(b0 + q) * 64;
    orow[k]      = o0 * rs;
    orow[16 + k] = o1 * rs;
    orow[32 + k] = o2 * rs;
    orow[48 + k] = o3 * rs;
}

extern "C" void kernel_launch(void* const* d_in, const int* in_sizes, int n_in,
                              void* d_out, int out_size, void* d_ws, size_t ws_size,
                              hipStream_t stream) {
    const float* x    = (const float*)d_in[0];   // [4096, 256, 64]
    const float* W    = (const float*)d_in[1];   // [64, 64]
    const float* U    = (const float*)d_in[2];   // [16, 64]
    const float* bias = (const float*)d_in[3];   // [64]
    const float* Wd   = (const float*)d_in[4];   // [16, 64]
    const float* bd   = (const float*)d_in[5];   // [64]
    float* out        = (float*)d_out;           // [4096, 64]

    const int n_rows = in_sizes[0] / ROW_ELEMS;  // 4096
    dim3 grid(n_rows / 4), block(64);            // 1024 single-wave blocks
    lstm_fused_kernel<<<grid, block, 0, stream>>>(x, W, U, bias, Wd, bd, out);
}